// Round 4
// baseline (435.081 us; speedup 1.0000x reference)
//
#include <hip/hip_runtime.h>
#include <stdint.h>
#include <math.h>

#define NBLK 512

// ---------------- ws float offsets ----------------
#define OFF_SCRP   0        // 3072  per-item SCR partials (feat0 0..2047, feat1 2048..3071)
#define OFF_MAINP  3072     // 32
#define OFF_IFDP   3104     // 1408  (feat2q 0..127, feat1 128..383, feat0 384..1407)
#define OFF_ARR    4512     // 8 ints (grid-barrier arrive counter at [0])
#define OFF_IDX    4520     // 192 ints (idx0[64], idx1[128])
#define OFF_WIDX0  4712     // 1024 ints
#define OFF_WIDX1  5736     // 2048 ints
#define OFF_WIDX2  7784     // 4096 ints -> 11880
#define OFF_NS0    11880    // 2048 (atomic-accumulated)
#define OFF_NS1    13928    // 4096
#define OFF_NS2    18024    // 8192 -> 26216
#define OFF_TOT    26216
// TIER2 partial tots in TOT: totp0 @0 (4x524288), totp1 @2097152 (8x131072), totp2 @3145728 (16x32768)
// TIER1 atomic tots in TOT:  tot0 @0 (524288),    tot1 @524288 (131072),    tot2 @655360 (32768)

// ---------------- Threefry-2x32-20 (exact JAX semantics) ----------------
__device__ __forceinline__ void tf_block(uint32_t k0, uint32_t k1, uint32_t& x0, uint32_t& x1) {
  uint32_t k2 = 0x1BD11BDAu ^ k0 ^ k1;
  x0 += k0; x1 += k1;
#define TFR(r) { x0 += x1; x1 = (x1 << r) | (x1 >> (32 - r)); x1 ^= x0; }
  TFR(13) TFR(15) TFR(26) TFR(6)
  x0 += k1; x1 += k2 + 1u;
  TFR(17) TFR(29) TFR(16) TFR(24)
  x0 += k2; x1 += k0 + 2u;
  TFR(13) TFR(15) TFR(26) TFR(6)
  x0 += k0; x1 += k1 + 3u;
  TFR(17) TFR(29) TFR(16) TFR(24)
  x0 += k1; x1 += k2 + 4u;
  TFR(13) TFR(15) TFR(26) TFR(6)
  x0 += k2; x1 += k0 + 5u;
#undef TFR
}

__device__ __forceinline__ float sigmoidf(float x) { return 1.0f / (1.0f + expf(-x)); }

// Block reduce (256 threads). Result valid on thread 0.
__device__ __forceinline__ float block_reduce(float v, float* red) {
  __syncthreads();
  int lane = threadIdx.x & 63, wv = threadIdx.x >> 6;
  for (int o = 32; o > 0; o >>= 1) v += __shfl_down(v, o, 64);
  if (lane == 0) red[wv] = v;
  __syncthreads();
  float r = 0.f;
  if (threadIdx.x == 0) r = red[0] + red[1] + red[2] + red[3];
  return r;
}

// Software grid barrier: monotonic arrive counter (zeroed by k0 each run).
// RELEASE add flushes this XCD's dirty L2 lines; relaxed agent-scope spin
// bypasses the non-coherent XCD L2; __threadfence() acquires after release.
__device__ __forceinline__ void gsync(int* arrive, int target) {
  __syncthreads();
  if (threadIdx.x == 0) {
    __hip_atomic_fetch_add(arrive, 1, __ATOMIC_RELEASE, __HIP_MEMORY_SCOPE_AGENT);
    int spins = 0;
    while (__hip_atomic_load(arrive, __ATOMIC_RELAXED, __HIP_MEMORY_SCOPE_AGENT) < target) {
      __builtin_amdgcn_s_sleep(8);
      if (++spins > 4000000) break;  // safety valve: fail visibly, never hang
    }
    __threadfence();
  }
  __syncthreads();
}

// ---------------- K0: perm + zero {arrive, ns arrays} ----------------
__global__ __launch_bounds__(256) void k0_perm(float* ws) {
  __shared__ uint32_t sub[2][2];
  __shared__ uint32_t bits[2][256];
  int t = threadIdx.x;
  // zero ns0+ns1+ns2 (14336 floats, contiguous, 16B-aligned) and arrive
  float4* nz = (float4*)(ws + OFF_NS0);
  for (int i = t; i < 3584; i += 256) nz[i] = float4{0.f, 0.f, 0.f, 0.f};
  if (t == 0) *(int*)(ws + OFF_ARR) = 0;
  int* idx0 = (int*)(ws + OFF_IDX);
  int* idx1 = idx0 + 64;
  if (t == 0) {
    for (int i = 0; i < 2; ++i) {
      uint32_t f0 = 0u, f1 = (uint32_t)i;          // fold_in(key(42), i)
      tf_block(0u, 42u, f0, f1);
      uint32_t a0 = 0u, a1 = 2u; tf_block(f0, f1, a0, a1);   // split -> kt
      uint32_t b0 = 1u, b1 = 3u; tf_block(f0, f1, b0, b1);
      uint32_t kt0 = a1, kt1 = b1;
      uint32_t c0 = 0u, c1 = 2u; tf_block(kt0, kt1, c0, c1); // split inside permutation
      uint32_t d0 = 1u, d1 = 3u; tf_block(kt0, kt1, d0, d1);
      sub[i][0] = c1; sub[i][1] = d1;
    }
  }
  __syncthreads();
  if (t < 128) {
    for (int i = 0; i < 2; ++i) {
      uint32_t x0 = (uint32_t)t, x1 = (uint32_t)(t + 128);
      tf_block(sub[i][0], sub[i][1], x0, x1);
      bits[i][t] = x0; bits[i][t + 128] = x1;
    }
  }
  __syncthreads();
  for (int i = 0; i < 2; ++i) {   // stable ascending rank = lax.sort_key_val
    uint32_t mine = bits[i][t];
    int rank = 0;
    for (int k = 0; k < 256; ++k) {
      uint32_t v = bits[i][k];
      rank += (v < mine) || (v == mine && k < t);
    }
    int lim = (i == 0) ? 64 : 128;
    if (rank < lim) { (i == 0 ? idx0 : idx1)[rank] = t; }
  }
}

// ---------------- fused persistent kernel ----------------
template<int TIER>
__global__ __launch_bounds__(256, 2) void kfused(
    const float* __restrict__ f0, const float* __restrict__ f1, const float* __restrict__ f2,
    const float* __restrict__ pred, const int* __restrict__ target,
    float* __restrict__ ws, float* __restrict__ out) {
  __shared__ float nsp[4096];
  __shared__ int sidx[128];
  __shared__ float red[8];
  const int bid = blockIdx.x, t = threadIdx.x;
  const int lane = t & 63, wv = t >> 6;

  float* scrp  = ws + OFF_SCRP;
  float* mainp = ws + OFF_MAINP;
  float* ifdp  = ws + OFF_IFDP;
  int* arrive  = (int*)(ws + OFF_ARR);
  const int* idxg = (const int*)(ws + OFF_IDX);
  int* widx0 = (int*)(ws + OFF_WIDX0);
  int* widx1 = (int*)(ws + OFF_WIDX1);
  int* widx2 = (int*)(ws + OFF_WIDX2);
  float* ns0 = ws + OFF_NS0;
  float* ns1 = ws + OFF_NS1;
  float* ns2 = ws + OFF_NS2;
  float* totb = ws + OFF_TOT;
  int bar = 0;

  if (TIER == 1) {  // zero atomic tot region: 688128 floats = 172032 float4
    for (int i = bid * 256 + t; i < 172032; i += NBLK * 256)
      ((float4*)totb)[i] = float4{0.f, 0.f, 0.f, 0.f};
    gsync(arrive, NBLK * (++bar));
  }

  // ================= P1: norms + SCR + tot partials + main loss =================
  for (int item = bid; item < 3616; item += NBLK) {
    __syncthreads();  // protect shared reuse across items
    if (item < 2048) {
      // ---- feat0: 32 x 64 x 128x128; item = (b, 1024px chunk, 16-ch group) ----
      int q = item, b = q >> 6, r = q & 63, chunk = r >> 2, cg_ = r & 3;
      if (t < 16) sidx[t] = idxg[cg_ * 16 + t];
      __syncthreads();
      const float* fb = f0 + (size_t)b * 1048576 + (size_t)cg_ * 262144 + chunk * 1024;
      const float* tb = f2 + (size_t)b * 262144 + (chunk * 2 + (t >> 7)) * 32 + (t & 31);
      float4 tot = {0.f, 0.f, 0.f, 0.f};
      float scr = 0.f;
      #pragma unroll
      for (int c = 0; c < 16; ++c) {
        float4 v = ((const float4*)(fb + (size_t)c * 16384))[t];
        float tv = tb[(size_t)sidx[c] * 1024];
        tot.x += v.x; tot.y += v.y; tot.z += v.z; tot.w += v.w;
        nsp[c * 256 + t] = v.x * v.x + v.y * v.y + v.z * v.z + v.w * v.w;
        float dx = v.x - tv, dy = v.y - tv, dz = v.z - tv, dw = v.w - tv;
        scr += dx * dx + dy * dy + dz * dz + dw * dw;
      }
      __syncthreads();
      #pragma unroll
      for (int j = 0; j < 4; ++j) {
        int c = wv * 4 + j;
        float s = nsp[c * 256 + lane] + nsp[c * 256 + lane + 64] +
                  nsp[c * 256 + lane + 128] + nsp[c * 256 + lane + 192];
        #pragma unroll
        for (int o = 32; o > 0; o >>= 1) s += __shfl_down(s, o, 64);
        if (lane == 0) atomicAdd(&ns0[b * 64 + cg_ * 16 + c], s);
      }
      if (TIER == 2) {
        ((float4*)(totb + (size_t)cg_ * 524288 + (size_t)b * 16384 + chunk * 1024))[t] = tot;
      } else if (TIER == 1) {
        float* tp = totb + (size_t)b * 16384 + chunk * 1024 + t * 4;
        atomicAdd(tp, tot.x); atomicAdd(tp + 1, tot.y);
        atomicAdd(tp + 2, tot.z); atomicAdd(tp + 3, tot.w);
      }
      float rr = block_reduce(scr, red);
      if (t == 0) scrp[item] = rr;

    } else if (item < 3072) {
      // ---- feat1: 32 x 128 x 64x64 ----
      int q = item - 2048, b = q >> 5, r = q & 31, chunk = r >> 3, cg_ = r & 7;
      if (t < 16) sidx[t] = idxg[64 + cg_ * 16 + t];
      __syncthreads();
      const float* fb = f1 + (size_t)b * 524288 + (size_t)cg_ * 65536 + chunk * 1024;
      const float* tb = f2 + (size_t)b * 262144 + (chunk * 8 + (t >> 5)) * 32 + (t & 15) * 2;
      float4 tot = {0.f, 0.f, 0.f, 0.f};
      float scr = 0.f;
      #pragma unroll
      for (int c = 0; c < 16; ++c) {
        float4 v = ((const float4*)(fb + (size_t)c * 4096))[t];
        float2 tv = *(const float2*)(tb + (size_t)sidx[c] * 1024);
        tot.x += v.x; tot.y += v.y; tot.z += v.z; tot.w += v.w;
        nsp[c * 256 + t] = v.x * v.x + v.y * v.y + v.z * v.z + v.w * v.w;
        float dx = v.x - tv.x, dy = v.y - tv.x, dz = v.z - tv.y, dw = v.w - tv.y;
        scr += dx * dx + dy * dy + dz * dz + dw * dw;
      }
      __syncthreads();
      #pragma unroll
      for (int j = 0; j < 4; ++j) {
        int c = wv * 4 + j;
        float s = nsp[c * 256 + lane] + nsp[c * 256 + lane + 64] +
                  nsp[c * 256 + lane + 128] + nsp[c * 256 + lane + 192];
        #pragma unroll
        for (int o = 32; o > 0; o >>= 1) s += __shfl_down(s, o, 64);
        if (lane == 0) atomicAdd(&ns1[b * 128 + cg_ * 16 + c], s);
      }
      if (TIER == 2) {
        ((float4*)(totb + 2097152 + (size_t)cg_ * 131072 + (size_t)b * 4096 + chunk * 1024))[t] = tot;
      } else if (TIER == 1) {
        float* tp = totb + 524288 + (size_t)b * 4096 + chunk * 1024 + t * 4;
        atomicAdd(tp, tot.x); atomicAdd(tp + 1, tot.y);
        atomicAdd(tp + 2, tot.z); atomicAdd(tp + 3, tot.w);
      }
      float rr = block_reduce(scr, red);
      if (t == 0) scrp[item] = rr;

    } else if (item < 3584) {
      // ---- feat2 (teacher): 32 x 256 x 32x32; item = (b, 16-ch group) ----
      int q = item - 3072, b = q >> 4, cg_ = q & 15;
      const float* fb = f2 + (size_t)b * 262144 + (size_t)cg_ * 16384;
      float4 tot = {0.f, 0.f, 0.f, 0.f};
      #pragma unroll
      for (int c = 0; c < 16; ++c) {
        float4 v = ((const float4*)(fb + (size_t)c * 1024))[t];
        tot.x += v.x; tot.y += v.y; tot.z += v.z; tot.w += v.w;
        nsp[c * 256 + t] = v.x * v.x + v.y * v.y + v.z * v.z + v.w * v.w;
      }
      __syncthreads();
      #pragma unroll
      for (int j = 0; j < 4; ++j) {
        int c = wv * 4 + j;
        float s = nsp[c * 256 + lane] + nsp[c * 256 + lane + 64] +
                  nsp[c * 256 + lane + 128] + nsp[c * 256 + lane + 192];
        #pragma unroll
        for (int o = 32; o > 0; o >>= 1) s += __shfl_down(s, o, 64);
        if (lane == 0) ns2[b * 256 + cg_ * 16 + c] = s;  // single writer per entry
      }
      if (TIER == 2) {
        ((float4*)(totb + 3145728 + (size_t)cg_ * 32768 + (size_t)b * 1024))[t] = tot;
      } else if (TIER == 1) {
        float* tp = totb + 655360 + (size_t)b * 1024 + t * 4;
        atomicAdd(tp, tot.x); atomicAdd(tp + 1, tot.y);
        atomicAdd(tp + 2, tot.z); atomicAdd(tp + 3, tot.w);
      }

    } else {
      // ---- main loss, one batch row ----
      int b = item - 3584;
      const float* row = pred + b * 1000;
      float m = -INFINITY;
      for (int j = t; j < 1000; j += 256) m = fmaxf(m, row[j]);
      nsp[t] = m; __syncthreads();
      for (int s = 128; s > 0; s >>= 1) { if (t < s) nsp[t] = fmaxf(nsp[t], nsp[t + s]); __syncthreads(); }
      m = nsp[0]; __syncthreads();
      float e = 0.f;
      for (int j = t; j < 1000; j += 256) e += expf(row[j] - m);
      nsp[t] = e; __syncthreads();
      for (int s = 128; s > 0; s >>= 1) { if (t < s) nsp[t] += nsp[t + s]; __syncthreads(); }
      if (t == 0) mainp[b] = logf(nsp[0]) + m - row[target[b]];
    }
  }
  gsync(arrive, NBLK * (++bar));

  // ================= P2: ranks (stable descending) + weak lists =================
  if (bid < 96) {
    float* nm = nsp;
    float* wk = nsp + 256;
    const float* nsg; int* widx; int C, b;
    if (bid < 32)      { nsg = ns0; widx = widx0; C = 64;  b = bid; }
    else if (bid < 64) { nsg = ns1; widx = widx1; C = 128; b = bid - 32; }
    else               { nsg = ns2; widx = widx2; C = 256; b = bid - 64; }
    if (t < C) nm[t] = sqrtf(nsg[b * C + t]);
    __syncthreads();
    if (t < C) {
      float mine = nm[t];
      int rank = 0;
      for (int k = 0; k < C; ++k) {
        float v = nm[k];
        rank += (v > mine) || (v == mine && k < t);
      }
      wk[t] = (rank >= C / 2) ? 1.f : 0.f;
    }
    __syncthreads();
    if (t < C && wk[t] > 0.5f) {
      int pos = 0;
      for (int k = 0; k < t; ++k) pos += (int)wk[k];
      widx[b * (C / 2) + pos] = t;   // weak channels (membership is all that matters)
    }
  }
  gsync(arrive, NBLK * (++bar));

  // ================= P3: IFD (weak half; strong = tot - weak) =================
  for (int i = bid; i < 1408; i += NBLK) {
    __syncthreads();
    if (i < 128) {
      // ---- feat2 quarter-plane: 128 weak ch x 256 px, scalar ----
      int b = i >> 2, qtr = i & 3;
      if (t < 128) sidx[t] = widx2[b * 128 + t];
      __syncthreads();
      const float* base = f2 + (size_t)b * 262144 + qtr * 256;
      float wkv = 0.f, tt = 0.f;
      if (TIER > 0) {
        #pragma unroll 8
        for (int k = 0; k < 128; ++k) wkv += base[(size_t)sidx[k] * 1024 + t];
        if (TIER == 2) {
          #pragma unroll
          for (int p = 0; p < 16; ++p) tt += totb[3145728 + (size_t)p * 32768 + b * 1024 + qtr * 256 + t];
        } else {
          tt = totb[655360 + (size_t)b * 1024 + qtr * 256 + t];
        }
      } else {
        float* wf = nsp;
        wf[t] = 0.f;
        __syncthreads();
        if (t < 128) wf[sidx[t]] = 1.f;
        __syncthreads();
        #pragma unroll 4
        for (int c = 0; c < 256; ++c) {
          float v = base[(size_t)c * 1024 + t];
          tt += v; wkv = fmaf(v, wf[c], wkv);
        }
      }
      float d = sigmoidf(wkv * (1.f / 128.f)) - sigmoidf((tt - wkv) * (1.f / 128.f));
      float r = block_reduce(d * d, red);
      if (t == 0) ifdp[i] = r;

    } else if (i < 384) {
      // ---- feat1: 64 weak ch x 512 px, float2 ----
      int q = i - 128, b = q >> 3, ch = q & 7;
      if (t < 64) sidx[t] = widx1[b * 64 + t];
      __syncthreads();
      const float2* base2 = (const float2*)(f1 + (size_t)b * 524288 + ch * 512);
      float2 wk2 = {0.f, 0.f}, tt2 = {0.f, 0.f};
      if (TIER > 0) {
        #pragma unroll 8
        for (int k = 0; k < 64; ++k) {
          float2 v = base2[(size_t)sidx[k] * 2048 + t];
          wk2.x += v.x; wk2.y += v.y;
        }
        if (TIER == 2) {
          #pragma unroll
          for (int p = 0; p < 8; ++p) {
            float2 v = ((const float2*)(totb + 2097152 + (size_t)p * 131072 + (size_t)b * 4096 + ch * 512))[t];
            tt2.x += v.x; tt2.y += v.y;
          }
        } else {
          tt2 = ((const float2*)(totb + 524288 + (size_t)b * 4096 + ch * 512))[t];
        }
      } else {
        float* wf = nsp;
        if (t < 128) wf[t] = 0.f;
        __syncthreads();
        if (t < 64) wf[sidx[t]] = 1.f;
        __syncthreads();
        #pragma unroll 4
        for (int c = 0; c < 128; ++c) {
          float2 v = base2[(size_t)c * 2048 + t];
          float f = wf[c];
          tt2.x += v.x; tt2.y += v.y;
          wk2.x = fmaf(v.x, f, wk2.x); wk2.y = fmaf(v.y, f, wk2.y);
        }
      }
      float s = 0.f, d;
      d = sigmoidf(wk2.x * (1.f / 64.f)) - sigmoidf((tt2.x - wk2.x) * (1.f / 64.f)); s += d * d;
      d = sigmoidf(wk2.y * (1.f / 64.f)) - sigmoidf((tt2.y - wk2.y) * (1.f / 64.f)); s += d * d;
      float r = block_reduce(s, red);
      if (t == 0) ifdp[i] = r;

    } else {
      // ---- feat0: 32 weak ch x 512 px, float2 ----
      int q = i - 384, b = q >> 5, ch = q & 31;
      if (t < 32) sidx[t] = widx0[b * 32 + t];
      __syncthreads();
      const float2* base2 = (const float2*)(f0 + (size_t)b * 1048576 + ch * 512);
      float2 wk2 = {0.f, 0.f}, tt2 = {0.f, 0.f};
      if (TIER > 0) {
        #pragma unroll 8
        for (int k = 0; k < 32; ++k) {
          float2 v = base2[(size_t)sidx[k] * 8192 + t];
          wk2.x += v.x; wk2.y += v.y;
        }
        if (TIER == 2) {
          #pragma unroll
          for (int p = 0; p < 4; ++p) {
            float2 v = ((const float2*)(totb + (size_t)p * 524288 + (size_t)b * 16384 + ch * 512))[t];
            tt2.x += v.x; tt2.y += v.y;
          }
        } else {
          tt2 = ((const float2*)(totb + (size_t)b * 16384 + ch * 512))[t];
        }
      } else {
        float* wf = nsp;
        if (t < 64) wf[t] = 0.f;
        __syncthreads();
        if (t < 32) wf[sidx[t]] = 1.f;
        __syncthreads();
        #pragma unroll 4
        for (int c = 0; c < 64; ++c) {
          float2 v = base2[(size_t)c * 8192 + t];
          float f = wf[c];
          tt2.x += v.x; tt2.y += v.y;
          wk2.x = fmaf(v.x, f, wk2.x); wk2.y = fmaf(v.y, f, wk2.y);
        }
      }
      float s = 0.f, d;
      d = sigmoidf(wk2.x * (1.f / 32.f)) - sigmoidf((tt2.x - wk2.x) * (1.f / 32.f)); s += d * d;
      d = sigmoidf(wk2.y * (1.f / 32.f)) - sigmoidf((tt2.y - wk2.y) * (1.f / 32.f)); s += d * d;
      float r = block_reduce(s, red);
      if (t == 0) ifdp[i] = r;
    }
  }
  gsync(arrive, NBLK * (++bar));

  // ================= P4: finalize =================
  if (bid == 0) {
    float s0 = 0.f, s1 = 0.f, i0 = 0.f, i1 = 0.f, i2 = 0.f, mn = 0.f;
    for (int i = t; i < 2048; i += 256) s0 += scrp[i];
    for (int i = 2048 + t; i < 3072; i += 256) s1 += scrp[i];
    for (int i = t; i < 128; i += 256) i2 += ifdp[i];
    for (int i = 128 + t; i < 384; i += 256) i1 += ifdp[i];
    for (int i = 384 + t; i < 1408; i += 256) i0 += ifdp[i];
    if (t < 32) mn = mainp[t];
    s0 = block_reduce(s0, red);
    s1 = block_reduce(s1, red);
    i0 = block_reduce(i0, red);
    i1 = block_reduce(i1, red);
    i2 = block_reduce(i2, red);
    mn = block_reduce(mn, red);
    if (t == 0) {
      float scr0 = s0 * (1.0f / (32.0f * 64.0f * 128.0f * 128.0f));
      float scr1 = s1 * (1.0f / (32.0f * 128.0f * 64.0f * 64.0f));
      float l_scr = 0.5f * (scr0 + scr1);
      float ifd0 = i0 * (1.0f / (32.0f * 128.0f * 128.0f));
      float ifd1 = i1 * (1.0f / (32.0f * 64.0f * 64.0f));
      float ifd2 = i2 * (1.0f / (32.0f * 32.0f * 32.0f));
      float l_ifd = (ifd0 + ifd1 + ifd2) * (1.0f / 3.0f);
      float l_main = mn * (1.0f / 32.0f);
      out[0] = l_main + 0.015f * l_scr + 0.015f * l_ifd;
      out[1] = l_main; out[2] = l_scr; out[3] = l_ifd;
    }
  }
}

extern "C" void kernel_launch(void* const* d_in, const int* in_sizes, int n_in,
                              void* d_out, int out_size, void* d_ws, size_t ws_size,
                              hipStream_t stream) {
  (void)in_sizes; (void)n_in; (void)out_size;
  const float* pred   = (const float*)d_in[0];
  const float* feat0  = (const float*)d_in[1];  // 32 x 64 x 128 x 128
  const float* feat1  = (const float*)d_in[2];  // 32 x 128 x 64 x 64
  const float* feat2  = (const float*)d_in[3];  // 32 x 256 x 32 x 32 (teacher)
  const int*   target = (const int*)d_in[4];
  float* ws  = (float*)d_ws;
  float* out = (float*)d_out;

  const size_t need_T1 = (size_t)(OFF_TOT + 688128) * 4;   // ~2.86 MB (< 3.01 MB proven)
  const size_t need_T2 = (size_t)(OFF_TOT + 3670016) * 4;  // ~14.8 MB

  k0_perm<<<1, 256, 0, stream>>>(ws);
  if (ws_size >= need_T2) {
    kfused<2><<<NBLK, 256, 0, stream>>>(feat0, feat1, feat2, pred, target, ws, out);
  } else if (ws_size == 0 || ws_size >= need_T1) {
    kfused<1><<<NBLK, 256, 0, stream>>>(feat0, feat1, feat2, pred, target, ws, out);
  } else {
    kfused<0><<<NBLK, 256, 0, stream>>>(feat0, feat1, feat2, pred, target, ws, out);
  }
}

// Round 5
// 316.348 us; speedup vs baseline: 1.3753x; 1.3753x over previous
//
#include <hip/hip_runtime.h>
#include <stdint.h>
#include <math.h>

// ---------------- ws float offsets ----------------
#define OFF_SCRP   0        // 3072: per-item SCR partials (feat0 0..2047, feat1 2048..3071)
#define OFF_MAINP  3072     // 32
#define OFF_IFDP   3104     // 1344 used (feat2 0..63, feat1 64..319, feat0 320..1343), pad to 1408
#define OFF_IDX    4512     // 192 ints (idx0[64], idx1[128])
#define OFF_WIDX0  4704     // 1024 ints
#define OFF_WIDX1  5728     // 2048 ints
#define OFF_WIDX2  7776     // 4096 ints -> 11872
#define OFF_NS0    11872    // 2048  (atomic-accumulated; zeroed by k0)
#define OFF_NS1    13920    // 4096
#define OFF_NS2    18016    // 8192 -> 26208
#define OFF_TOT    26208
// TIER2 tot partials: totp0 @0 (4 x 524288), totp1 @2097152 (8 x 131072), totp2 @3145728 (16 x 32768)
//   -> 3670016 floats; need_T2 = (26208+3670016)*4 = 14,784,896 B  (<= 14,784,928 proven in R4)
// TIER1 atomic tots:  tot0 @0 (524288), tot1 @524288 (131072), tot2 @655360 (32768) -> 688128 floats

// ---------------- Threefry-2x32-20 (exact JAX semantics) ----------------
__device__ __forceinline__ void tf_block(uint32_t k0, uint32_t k1, uint32_t& x0, uint32_t& x1) {
  uint32_t k2 = 0x1BD11BDAu ^ k0 ^ k1;
  x0 += k0; x1 += k1;
#define TFR(r) { x0 += x1; x1 = (x1 << r) | (x1 >> (32 - r)); x1 ^= x0; }
  TFR(13) TFR(15) TFR(26) TFR(6)
  x0 += k1; x1 += k2 + 1u;
  TFR(17) TFR(29) TFR(16) TFR(24)
  x0 += k2; x1 += k0 + 2u;
  TFR(13) TFR(15) TFR(26) TFR(6)
  x0 += k0; x1 += k1 + 3u;
  TFR(17) TFR(29) TFR(16) TFR(24)
  x0 += k1; x1 += k2 + 4u;
  TFR(13) TFR(15) TFR(26) TFR(6)
  x0 += k2; x1 += k0 + 5u;
#undef TFR
}

__device__ __forceinline__ float sigmoidf(float x) { return 1.0f / (1.0f + expf(-x)); }

// Block reduce (256 threads). Result valid on thread 0.
__device__ __forceinline__ float block_reduce(float v, float* red) {
  __syncthreads();
  int lane = threadIdx.x & 63, wv = threadIdx.x >> 6;
  for (int o = 32; o > 0; o >>= 1) v += __shfl_down(v, o, 64);
  if (lane == 0) red[wv] = v;
  __syncthreads();
  float r = 0.f;
  if (threadIdx.x == 0) r = red[0] + red[1] + red[2] + red[3];
  return r;
}

// ---------------- K0: perm + zero ns; (TIER1: blocks>0 zero atomic tot) ----------------
__global__ __launch_bounds__(256) void k0_perm(float* ws) {
  int t = threadIdx.x;
  if (blockIdx.x > 0) {  // TIER1 only: zero 688128 floats = 172032 float4 over 672 blocks
    ((float4*)(ws + OFF_TOT))[(blockIdx.x - 1) * 256 + t] = float4{0.f, 0.f, 0.f, 0.f};
    return;
  }
  __shared__ uint32_t sub[2][2];
  __shared__ uint32_t bits[2][256];
  // zero ns0+ns1+ns2 (14336 floats, 16B-aligned)
  float4* nz = (float4*)(ws + OFF_NS0);
  for (int i = t; i < 3584; i += 256) nz[i] = float4{0.f, 0.f, 0.f, 0.f};
  int* idx0 = (int*)(ws + OFF_IDX);
  int* idx1 = idx0 + 64;
  if (t == 0) {
    for (int i = 0; i < 2; ++i) {
      uint32_t f0 = 0u, f1 = (uint32_t)i;          // fold_in(key(42), i)
      tf_block(0u, 42u, f0, f1);
      uint32_t a0 = 0u, a1 = 2u; tf_block(f0, f1, a0, a1);   // split -> kt
      uint32_t b0 = 1u, b1 = 3u; tf_block(f0, f1, b0, b1);
      uint32_t kt0 = a1, kt1 = b1;
      uint32_t c0 = 0u, c1 = 2u; tf_block(kt0, kt1, c0, c1); // split inside permutation
      uint32_t d0 = 1u, d1 = 3u; tf_block(kt0, kt1, d0, d1);
      sub[i][0] = c1; sub[i][1] = d1;
    }
  }
  __syncthreads();
  if (t < 128) {
    for (int i = 0; i < 2; ++i) {
      uint32_t x0 = (uint32_t)t, x1 = (uint32_t)(t + 128);
      tf_block(sub[i][0], sub[i][1], x0, x1);
      bits[i][t] = x0; bits[i][t + 128] = x1;
    }
  }
  __syncthreads();
  for (int i = 0; i < 2; ++i) {   // stable ascending rank = lax.sort_key_val
    uint32_t mine = bits[i][t];
    int rank = 0;
    for (int k = 0; k < 256; ++k) {
      uint32_t v = bits[i][k];
      rank += (v < mine) || (v == mine && k < t);
    }
    int lim = (i == 0) ? 64 : 128;
    if (rank < lim) { (i == 0 ? idx0 : idx1)[rank] = t; }
  }
}

// ---------------- K1: pass1 (norms + SCR + tot partials) ----------------
// R2-proven inner loops. XCD-swizzled block->item maps co-locate the channel
// groups that share teacher rows on one XCD's L2 (round-robin heuristic;
// correctness-neutral bijections).
template<int TIER>
__global__ __launch_bounds__(256) void k1_pass1(
    const float* __restrict__ f0, const float* __restrict__ f1, const float* __restrict__ f2,
    float* __restrict__ ws) {
  __shared__ float nsp[4096];
  __shared__ int sidx[16];
  __shared__ float red[8];
  const int bid = blockIdx.x, t = threadIdx.x;
  const int lane = t & 63, wv = t >> 6;
  float* scrp = ws + OFF_SCRP;
  const int* idxg = (const int*)(ws + OFF_IDX);
  float* ns0 = ws + OFF_NS0;
  float* ns1 = ws + OFF_NS1;
  float* ns2 = ws + OFF_NS2;
  float* totb = ws + OFF_TOT;

  if (bid < 2048) {
    // ---- feat0: 32 x 64 x 128x128; groups of 4 consecutive q share teacher rows ----
    int xcd = bid & 7, s = bid >> 3, c4 = s & 3, ghi = s >> 2;      // ghi in [0,64)
    int q = (ghi * 8 + xcd) * 4 + c4;                               // bijection on [0,2048)
    int b = q >> 6, r = q & 63, chunk = r >> 2, cg_ = r & 3;
    if (t < 16) sidx[t] = idxg[cg_ * 16 + t];
    __syncthreads();
    const float* fb = f0 + (size_t)b * 1048576 + (size_t)cg_ * 262144 + chunk * 1024;
    const float* tb = f2 + (size_t)b * 262144 + (chunk * 2 + (t >> 7)) * 32 + (t & 31);
    float4 tot = {0.f, 0.f, 0.f, 0.f};
    float scr = 0.f;
    #pragma unroll
    for (int c = 0; c < 16; ++c) {
      float4 v = ((const float4*)(fb + (size_t)c * 16384))[t];
      float tv = tb[(size_t)sidx[c] * 1024];
      tot.x += v.x; tot.y += v.y; tot.z += v.z; tot.w += v.w;
      nsp[c * 256 + t] = v.x * v.x + v.y * v.y + v.z * v.z + v.w * v.w;
      float dx = v.x - tv, dy = v.y - tv, dz = v.z - tv, dw = v.w - tv;
      scr += dx * dx + dy * dy + dz * dz + dw * dw;
    }
    __syncthreads();
    #pragma unroll
    for (int j = 0; j < 4; ++j) {
      int c = wv * 4 + j;
      float s2 = nsp[c * 256 + lane] + nsp[c * 256 + lane + 64] +
                 nsp[c * 256 + lane + 128] + nsp[c * 256 + lane + 192];
      #pragma unroll
      for (int o = 32; o > 0; o >>= 1) s2 += __shfl_down(s2, o, 64);
      if (lane == 0) atomicAdd(&ns0[b * 64 + cg_ * 16 + c], s2);
    }
    if (TIER == 2) {
      ((float4*)(totb + (size_t)cg_ * 524288 + (size_t)b * 16384 + chunk * 1024))[t] = tot;
    } else if (TIER == 1) {
      float* tp = totb + (size_t)b * 16384 + chunk * 1024 + t * 4;
      atomicAdd(tp, tot.x); atomicAdd(tp + 1, tot.y);
      atomicAdd(tp + 2, tot.z); atomicAdd(tp + 3, tot.w);
    }
    float rr = block_reduce(scr, red);
    if (t == 0) scrp[q] = rr;

  } else if (bid < 3072) {
    // ---- feat1: 32 x 128 x 64x64; groups of 8 consecutive q share teacher rows ----
    int bb = bid - 2048;
    int xcd = bb & 7, s = bb >> 3, c8 = s & 7, ghi = s >> 3;        // ghi in [0,16)
    int q = (ghi * 8 + xcd) * 8 + c8;                               // bijection on [0,1024)
    int b = q >> 5, r = q & 31, chunk = r >> 3, cg_ = r & 7;
    if (t < 16) sidx[t] = idxg[64 + cg_ * 16 + t];
    __syncthreads();
    const float* fb = f1 + (size_t)b * 524288 + (size_t)cg_ * 65536 + chunk * 1024;
    const float* tb = f2 + (size_t)b * 262144 + (chunk * 8 + (t >> 5)) * 32 + (t & 15) * 2;
    float4 tot = {0.f, 0.f, 0.f, 0.f};
    float scr = 0.f;
    #pragma unroll
    for (int c = 0; c < 16; ++c) {
      float4 v = ((const float4*)(fb + (size_t)c * 4096))[t];
      float2 tv = *(const float2*)(tb + (size_t)sidx[c] * 1024);
      tot.x += v.x; tot.y += v.y; tot.z += v.z; tot.w += v.w;
      nsp[c * 256 + t] = v.x * v.x + v.y * v.y + v.z * v.z + v.w * v.w;
      float dx = v.x - tv.x, dy = v.y - tv.x, dz = v.z - tv.y, dw = v.w - tv.y;
      scr += dx * dx + dy * dy + dz * dz + dw * dw;
    }
    __syncthreads();
    #pragma unroll
    for (int j = 0; j < 4; ++j) {
      int c = wv * 4 + j;
      float s2 = nsp[c * 256 + lane] + nsp[c * 256 + lane + 64] +
                 nsp[c * 256 + lane + 128] + nsp[c * 256 + lane + 192];
      #pragma unroll
      for (int o = 32; o > 0; o >>= 1) s2 += __shfl_down(s2, o, 64);
      if (lane == 0) atomicAdd(&ns1[b * 128 + cg_ * 16 + c], s2);
    }
    if (TIER == 2) {
      ((float4*)(totb + 2097152 + (size_t)cg_ * 131072 + (size_t)b * 4096 + chunk * 1024))[t] = tot;
    } else if (TIER == 1) {
      float* tp = totb + 524288 + (size_t)b * 4096 + chunk * 1024 + t * 4;
      atomicAdd(tp, tot.x); atomicAdd(tp + 1, tot.y);
      atomicAdd(tp + 2, tot.z); atomicAdd(tp + 3, tot.w);
    }
    float rr = block_reduce(scr, red);
    if (t == 0) scrp[2048 + q] = rr;

  } else {
    // ---- feat2 (teacher): 32 x 256 x 32x32 ----
    int q = bid - 3072, b = q >> 4, cg_ = q & 15;
    const float* fb = f2 + (size_t)b * 262144 + (size_t)cg_ * 16384;
    float4 tot = {0.f, 0.f, 0.f, 0.f};
    #pragma unroll
    for (int c = 0; c < 16; ++c) {
      float4 v = ((const float4*)(fb + (size_t)c * 1024))[t];
      tot.x += v.x; tot.y += v.y; tot.z += v.z; tot.w += v.w;
      nsp[c * 256 + t] = v.x * v.x + v.y * v.y + v.z * v.z + v.w * v.w;
    }
    __syncthreads();
    #pragma unroll
    for (int j = 0; j < 4; ++j) {
      int c = wv * 4 + j;
      float s2 = nsp[c * 256 + lane] + nsp[c * 256 + lane + 64] +
                 nsp[c * 256 + lane + 128] + nsp[c * 256 + lane + 192];
      #pragma unroll
      for (int o = 32; o > 0; o >>= 1) s2 += __shfl_down(s2, o, 64);
      if (lane == 0) ns2[b * 256 + cg_ * 16 + c] = s2;  // single writer
    }
    if (TIER == 2) {
      ((float4*)(totb + 3145728 + (size_t)cg_ * 32768 + (size_t)b * 1024))[t] = tot;
    } else if (TIER == 1) {
      float* tp = totb + 655360 + (size_t)b * 1024 + t * 4;
      atomicAdd(tp, tot.x); atomicAdd(tp + 1, tot.y);
      atomicAdd(tp + 2, tot.z); atomicAdd(tp + 3, tot.w);
    }
  }
}

// ---------------- K2: ranks (stable descending) + weak lists + main loss ----------------
__global__ __launch_bounds__(256) void k2_rank_main(
    const float* __restrict__ pred, const int* __restrict__ target, float* __restrict__ ws) {
  __shared__ float sh[512];
  __shared__ float red[8];
  int bid = blockIdx.x, t = threadIdx.x;
  if (bid < 96) {
    float* nm = sh;
    float* wk = sh + 256;
    const float* nsg; int* widx; int C, b;
    if (bid < 32)      { nsg = ws + OFF_NS0; widx = (int*)(ws + OFF_WIDX0); C = 64;  b = bid; }
    else if (bid < 64) { nsg = ws + OFF_NS1; widx = (int*)(ws + OFF_WIDX1); C = 128; b = bid - 32; }
    else               { nsg = ws + OFF_NS2; widx = (int*)(ws + OFF_WIDX2); C = 256; b = bid - 64; }
    if (t < C) nm[t] = sqrtf(nsg[b * C + t]);
    __syncthreads();
    if (t < C) {
      float mine = nm[t];
      int rank = 0;
      for (int k = 0; k < C; ++k) {
        float v = nm[k];
        rank += (v > mine) || (v == mine && k < t);
      }
      if (rank >= C / 2) widx[b * (C / 2) + rank - C / 2] = t;  // weak = ranks [C/2, C)
    }
  } else {
    // main loss, one batch row per block
    int b = bid - 96;
    const float* row = pred + b * 1000;
    float m = -INFINITY;
    for (int j = t; j < 1000; j += 256) m = fmaxf(m, row[j]);
    sh[t] = m; __syncthreads();
    for (int s = 128; s > 0; s >>= 1) { if (t < s) sh[t] = fmaxf(sh[t], sh[t + s]); __syncthreads(); }
    m = sh[0]; __syncthreads();
    float e = 0.f;
    for (int j = t; j < 1000; j += 256) e += expf(row[j] - m);
    float r = block_reduce(e, red);
    if (t == 0) (ws + OFF_MAINP)[b] = logf(r) + m - row[target[b]];
  }
}

// ---------------- K3: pass2 (IFD, weak half; strong = tot - weak) ----------------
template<int TIER>
__global__ __launch_bounds__(256) void k3_pass2(
    const float* __restrict__ f0, const float* __restrict__ f1, const float* __restrict__ f2,
    float* __restrict__ ws) {
  __shared__ int sidx[128];
  __shared__ float wf[256];
  __shared__ float red[8];
  int bid = blockIdx.x, t = threadIdx.x;
  float* ifdp = ws + OFF_IFDP;
  const float* totb = ws + OFF_TOT;

  if (bid < 64) {
    // ---- feat2: 128 weak ch x 512 px (float2), 2 chunks/batch ----
    int b = bid >> 1, hf = bid & 1;
    const int* widx2 = (const int*)(ws + OFF_WIDX2);
    if (t < 128) sidx[t] = widx2[b * 128 + t];
    __syncthreads();
    const float2* base2 = (const float2*)(f2 + (size_t)b * 262144 + hf * 512);
    float2 wk2 = {0.f, 0.f}, tt2 = {0.f, 0.f};
    if (TIER > 0) {
      #pragma unroll 8
      for (int k = 0; k < 128; ++k) {
        float2 v = base2[(size_t)sidx[k] * 512 + t];
        wk2.x += v.x; wk2.y += v.y;
      }
      if (TIER == 2) {
        #pragma unroll
        for (int p = 0; p < 16; ++p) {
          float2 v = ((const float2*)(totb + 3145728 + (size_t)p * 32768 + (size_t)b * 1024 + hf * 512))[t];
          tt2.x += v.x; tt2.y += v.y;
        }
      } else {
        tt2 = ((const float2*)(totb + 655360 + (size_t)b * 1024 + hf * 512))[t];
      }
    } else {
      wf[t] = 0.f;
      __syncthreads();
      if (t < 128) wf[sidx[t]] = 1.f;
      __syncthreads();
      #pragma unroll 4
      for (int c = 0; c < 256; ++c) {
        float2 v = base2[(size_t)c * 512 + t];
        float f = wf[c];
        tt2.x += v.x; tt2.y += v.y;
        wk2.x = fmaf(v.x, f, wk2.x); wk2.y = fmaf(v.y, f, wk2.y);
      }
    }
    float s = 0.f, d;
    d = sigmoidf(wk2.x * (1.f / 128.f)) - sigmoidf((tt2.x - wk2.x) * (1.f / 128.f)); s += d * d;
    d = sigmoidf(wk2.y * (1.f / 128.f)) - sigmoidf((tt2.y - wk2.y) * (1.f / 128.f)); s += d * d;
    float r = block_reduce(s, red);
    if (t == 0) ifdp[bid] = r;

  } else if (bid < 320) {
    // ---- feat1: 64 weak ch x 512 px (float2), 8 chunks/batch ----
    int q = bid - 64, b = q >> 3, ch = q & 7;
    const int* widx1 = (const int*)(ws + OFF_WIDX1);
    if (t < 64) sidx[t] = widx1[b * 64 + t];
    __syncthreads();
    const float2* base2 = (const float2*)(f1 + (size_t)b * 524288 + ch * 512);
    float2 wk2 = {0.f, 0.f}, tt2 = {0.f, 0.f};
    if (TIER > 0) {
      #pragma unroll 8
      for (int k = 0; k < 64; ++k) {
        float2 v = base2[(size_t)sidx[k] * 2048 + t];
        wk2.x += v.x; wk2.y += v.y;
      }
      if (TIER == 2) {
        #pragma unroll
        for (int p = 0; p < 8; ++p) {
          float2 v = ((const float2*)(totb + 2097152 + (size_t)p * 131072 + (size_t)b * 4096 + ch * 512))[t];
          tt2.x += v.x; tt2.y += v.y;
        }
      } else {
        tt2 = ((const float2*)(totb + 524288 + (size_t)b * 4096 + ch * 512))[t];
      }
    } else {
      if (t < 128) wf[t] = 0.f;
      __syncthreads();
      if (t < 64) wf[sidx[t]] = 1.f;
      __syncthreads();
      #pragma unroll 4
      for (int c = 0; c < 128; ++c) {
        float2 v = base2[(size_t)c * 2048 + t];
        float f = wf[c];
        tt2.x += v.x; tt2.y += v.y;
        wk2.x = fmaf(v.x, f, wk2.x); wk2.y = fmaf(v.y, f, wk2.y);
      }
    }
    float s = 0.f, d;
    d = sigmoidf(wk2.x * (1.f / 64.f)) - sigmoidf((tt2.x - wk2.x) * (1.f / 64.f)); s += d * d;
    d = sigmoidf(wk2.y * (1.f / 64.f)) - sigmoidf((tt2.y - wk2.y) * (1.f / 64.f)); s += d * d;
    float r = block_reduce(s, red);
    if (t == 0) ifdp[bid] = r;

  } else {
    // ---- feat0: 32 weak ch x 512 px (float2), 32 chunks/batch ----
    int q = bid - 320, b = q >> 5, ch = q & 31;
    const int* widx0 = (const int*)(ws + OFF_WIDX0);
    if (t < 32) sidx[t] = widx0[b * 32 + t];
    __syncthreads();
    const float2* base2 = (const float2*)(f0 + (size_t)b * 1048576 + ch * 512);
    float2 wk2 = {0.f, 0.f}, tt2 = {0.f, 0.f};
    if (TIER > 0) {
      #pragma unroll 8
      for (int k = 0; k < 32; ++k) {
        float2 v = base2[(size_t)sidx[k] * 8192 + t];
        wk2.x += v.x; wk2.y += v.y;
      }
      if (TIER == 2) {
        #pragma unroll
        for (int p = 0; p < 4; ++p) {
          float2 v = ((const float2*)(totb + (size_t)p * 524288 + (size_t)b * 16384 + ch * 512))[t];
          tt2.x += v.x; tt2.y += v.y;
        }
      } else {
        tt2 = ((const float2*)(totb + (size_t)b * 16384 + ch * 512))[t];
      }
    } else {
      if (t < 64) wf[t] = 0.f;
      __syncthreads();
      if (t < 32) wf[sidx[t]] = 1.f;
      __syncthreads();
      #pragma unroll 4
      for (int c = 0; c < 64; ++c) {
        float2 v = base2[(size_t)c * 8192 + t];
        float f = wf[c];
        tt2.x += v.x; tt2.y += v.y;
        wk2.x = fmaf(v.x, f, wk2.x); wk2.y = fmaf(v.y, f, wk2.y);
      }
    }
    float s = 0.f, d;
    d = sigmoidf(wk2.x * (1.f / 32.f)) - sigmoidf((tt2.x - wk2.x) * (1.f / 32.f)); s += d * d;
    d = sigmoidf(wk2.y * (1.f / 32.f)) - sigmoidf((tt2.y - wk2.y) * (1.f / 32.f)); s += d * d;
    float r = block_reduce(s, red);
    if (t == 0) ifdp[bid] = r;
  }
}

// ---------------- K4: finalize ----------------
__global__ __launch_bounds__(256) void k4_finalize(const float* __restrict__ ws, float* __restrict__ out) {
  __shared__ float red[8];
  int t = threadIdx.x;
  const float* scrp  = ws + OFF_SCRP;
  const float* mainp = ws + OFF_MAINP;
  const float* ifdp  = ws + OFF_IFDP;
  float s0 = 0.f, s1 = 0.f, i0 = 0.f, i1 = 0.f, i2 = 0.f, mn = 0.f;
  for (int i = t; i < 2048; i += 256) s0 += scrp[i];
  for (int i = 2048 + t; i < 3072; i += 256) s1 += scrp[i];
  for (int i = t; i < 64; i += 256) i2 += ifdp[i];
  for (int i = 64 + t; i < 320; i += 256) i1 += ifdp[i];
  for (int i = 320 + t; i < 1344; i += 256) i0 += ifdp[i];
  if (t < 32) mn = mainp[t];
  s0 = block_reduce(s0, red);
  s1 = block_reduce(s1, red);
  i0 = block_reduce(i0, red);
  i1 = block_reduce(i1, red);
  i2 = block_reduce(i2, red);
  mn = block_reduce(mn, red);
  if (t == 0) {
    float scr0 = s0 * (1.0f / (32.0f * 64.0f * 128.0f * 128.0f));
    float scr1 = s1 * (1.0f / (32.0f * 128.0f * 64.0f * 64.0f));
    float l_scr = 0.5f * (scr0 + scr1);
    float ifd0 = i0 * (1.0f / (32.0f * 128.0f * 128.0f));
    float ifd1 = i1 * (1.0f / (32.0f * 64.0f * 64.0f));
    float ifd2 = i2 * (1.0f / (32.0f * 32.0f * 32.0f));
    float l_ifd = (ifd0 + ifd1 + ifd2) * (1.0f / 3.0f);
    float l_main = mn * (1.0f / 32.0f);
    out[0] = l_main + 0.015f * l_scr + 0.015f * l_ifd;
    out[1] = l_main; out[2] = l_scr; out[3] = l_ifd;
  }
}

extern "C" void kernel_launch(void* const* d_in, const int* in_sizes, int n_in,
                              void* d_out, int out_size, void* d_ws, size_t ws_size,
                              hipStream_t stream) {
  (void)in_sizes; (void)n_in; (void)out_size;
  const float* pred   = (const float*)d_in[0];
  const float* feat0  = (const float*)d_in[1];  // 32 x 64 x 128 x 128
  const float* feat1  = (const float*)d_in[2];  // 32 x 128 x 64 x 64
  const float* feat2  = (const float*)d_in[3];  // 32 x 256 x 32 x 32 (teacher)
  const int*   target = (const int*)d_in[4];
  float* ws  = (float*)d_ws;
  float* out = (float*)d_out;

  const size_t need_T2 = (size_t)(OFF_TOT + 3670016) * 4;  // 14,784,896 B (proven available R4)
  const size_t need_T1 = (size_t)(OFF_TOT + 688128) * 4;   // ~2.86 MB   (proven available R2)

  int tier;
  if (ws_size >= need_T2)                      tier = 2;
  else if (ws_size == 0 || ws_size >= need_T1) tier = 1;
  else                                         tier = 0;

  k0_perm<<<(tier == 1) ? 673 : 1, 256, 0, stream>>>(ws);
  if (tier == 2) {
    k1_pass1<2><<<3584, 256, 0, stream>>>(feat0, feat1, feat2, ws);
    k2_rank_main<<<128, 256, 0, stream>>>(pred, target, ws);
    k3_pass2<2><<<1344, 256, 0, stream>>>(feat0, feat1, feat2, ws);
  } else if (tier == 1) {
    k1_pass1<1><<<3584, 256, 0, stream>>>(feat0, feat1, feat2, ws);
    k2_rank_main<<<128, 256, 0, stream>>>(pred, target, ws);
    k3_pass2<1><<<1344, 256, 0, stream>>>(feat0, feat1, feat2, ws);
  } else {
    k1_pass1<0><<<3584, 256, 0, stream>>>(feat0, feat1, feat2, ws);
    k2_rank_main<<<128, 256, 0, stream>>>(pred, target, ws);
    k3_pass2<0><<<1344, 256, 0, stream>>>(feat0, feat1, feat2, ws);
  }
  k4_finalize<<<1, 256, 0, stream>>>(ws, out);
}